// Round 19
// baseline (44.012 us; speedup 1.0000x reference)
//
#include <hip/hip_runtime.h>

typedef unsigned short u16;
typedef unsigned int u32;
typedef __attribute__((ext_vector_type(2))) unsigned int u32x2;
typedef __attribute__((ext_vector_type(4))) unsigned short u16x4;
typedef __attribute__((ext_vector_type(8))) unsigned short u16x8;
typedef __attribute__((ext_vector_type(4))) float f32x4;

#define QN 512
#define SN 128
#define DN 512
#define QT 8192   /* query frames */
#define STF 2048  /* support frames */

#if __has_builtin(__builtin_amdgcn_exp2f)
#define EXP2F __builtin_amdgcn_exp2f
#else
#define EXP2F exp2f
#endif
#if __has_builtin(__builtin_amdgcn_logf)
#define LOG2F __builtin_amdgcn_logf
#else
#define LOG2F log2f
#endif

#define KEXP 2.8853900817779268f     /* 1/(lbda*ln2), lbda=0.5 */
#define KEXPS (KEXP/256.0f)          /* compensates the x16 input scaling (16*16) */
#define CLOG 0.34657359027997264f    /* lbda*ln2 */
#define K2   7.38905609893065f       /* exp(1/lbda) = e^2 */
#define BUFSZ 49152u                 /* A 32KB + B 16KB per K=128 fp8 tile */

__device__ __forceinline__ u16 f2bf(float f){
  union { float f; unsigned int u; } v; v.f = f;
  unsigned int u = v.u;
  unsigned int r = (u + 0x7fffu + ((u >> 16) & 1u)) >> 16;
  return (u16)r;
}
__device__ __forceinline__ float bf2f(u16 v){
  union { unsigned int u; float f; } x; x.u = ((unsigned int)v) << 16; return x.f;
}

// f32 -> OCP e4m3fn, RNE; flush |x| < 2^-6 to +-0 (values here are ~N(0,0.7), max ~4)
__device__ __forceinline__ u32 f2e4m3(float x){
  union { float f; u32 u; } v; v.f = x;
  u32 s = (v.u >> 24) & 0x80u;
  float a = fabsf(x);
  if (a < 0.015625f) return s;
  u32 au = v.u & 0x7FFFFFFFu;
  u32 r = au + 0x7FFFFu + ((au >> 20) & 1u);   // RNE at mantissa bit 20
  u32 e = (r >> 23) - 127u + 7u;
  u32 m = (r >> 20) & 7u;
  return s | (e << 3) | m;
}

__device__ __forceinline__ void gld16(const void* g, unsigned lds_addr){
  __builtin_amdgcn_global_load_lds(
      (const __attribute__((address_space(1))) unsigned int*)(unsigned long long)g,
      (__attribute__((address_space(3))) unsigned int*)lds_addr,
      16, 0, 0);
}

// ---------------- prep: f32 -> fp8 e4m3 of 16*row/||row|| ----------------
__global__ __launch_bounds__(256) void prep_kernel(
    const float* __restrict__ sup, const float* __restrict__ tgt,
    char* __restrict__ A8, char* __restrict__ B8)
{
  int w = (int)((blockIdx.x * blockDim.x + threadIdx.x) >> 6);
  int lane = threadIdx.x & 63;
  if (w >= QT + STF) return;
  bool isQ = (w < QT);
  int row = isQ ? w : (w - QT);
  const float* src = (isQ ? tgt : sup) + (size_t)row * DN + lane * 8;
  f32x4 x0 = *(const f32x4*)src;
  f32x4 x1 = *(const f32x4*)(src + 4);
  float ss = 0.f;
  #pragma unroll
  for (int i = 0; i < 4; ++i) { ss += x0[i]*x0[i]; ss += x1[i]*x1[i]; }
  #pragma unroll
  for (int off = 32; off; off >>= 1) ss += __shfl_xor(ss, off);
  float inv = __builtin_amdgcn_rsqf(ss) * 16.0f;   // x16: dodge e4m3 subnormals
  u32 lo = 0, hi = 0;
  #pragma unroll
  for (int i = 0; i < 4; ++i) { lo |= f2e4m3(x0[i]*inv) << (8*i); hi |= f2e4m3(x1[i]*inv) << (8*i); }
  u32x2 o; o[0] = lo; o[1] = hi;
  char* dst = (isQ ? A8 : B8) + (size_t)row * DN + lane * 8;
  *(u32x2*)dst = o;
}

// ---------------- fused: 256x128 fp8 GEMM, 16 WAVES (wave tile 64x32), BK=128 --------
// R15's proven schedule at double the wave count: acc[4][2]=32 regs so the whole
// kernel fits the 128-reg cap a 1024-thread block requires -> 4 waves/SIMD at
// 1 block/CU (vs R15's 2). Single epilogue: acc dies before DP for ALL waves
// (no R9/R17 liveness wall). Triple-buffer depth-2, vmcnt(3) (3 loads/wave/tile),
// ONE barrier per tile; same swizzles, dt formula, XCD chunking as R15.
__global__ __launch_bounds__(1024) void fused_kernel(
    const char* __restrict__ A8, const char* __restrict__ B8,
    float* __restrict__ out)
{
  __shared__ __align__(128) char smem[147456];
  const int t = threadIdx.x;
  // XCD swizzle: 512 blocks, 64 consecutive work-ids per XCD
  const int bid = blockIdx.x;
  const int wsw = (bid & 7) * 64 + (bid >> 3);
  const int bx = wsw & 15, by = wsw >> 4;
  const int m0 = by * 256;   // query-frame base
  const int n0 = bx * 128;   // support-frame base
  const int wave = t >> 6, lane = t & 63;
  const int wr = wave >> 2, wc = wave & 3;   // 4x4 wave grid; wave tile 64x32
  const int lhi = lane >> 4, llo = lane & 15;

  const unsigned sbase = (unsigned)(unsigned long long)(void*)smem;

  // staging: row = 128B fp8 (K=128). gld16 = 8 rows x 8 granules of 16B;
  // lane>>3 = row-sub, lane&7 = phys granule holding logical (lane&7)^rowsub.
  // Per wave/tile: A rows [wave*16,+16) = 2 gld16, B rows [wave*8,+8) = 1 gld16.
  const int rsub = lane >> 3;
  const int lp = (lane & 7) ^ rsub;
  const char* pA0 = A8 + (size_t)(m0 + wave*16 + 0 + rsub) * DN + lp*16;
  const char* pA1 = A8 + (size_t)(m0 + wave*16 + 8 + rsub) * DN + lp*16;
  const char* pB0 = B8 + (size_t)(n0 + wave*8  +     rsub) * DN + lp*16;
  const unsigned ldsA0 = __builtin_amdgcn_readfirstlane(sbase + (unsigned)(wave*2048));
  const unsigned ldsA1 = __builtin_amdgcn_readfirstlane(sbase + (unsigned)(wave*2048 + 1024));
  const unsigned ldsB0 = __builtin_amdgcn_readfirstlane(sbase + 32768u + (unsigned)(wave*1024));

  f32x4 acc[4][2] = {};

  auto STAGE = [&](unsigned bo, int koff) {
    gld16(pA0 + koff, ldsA0 + bo);
    gld16(pA1 + koff, ldsA1 + bo);
    gld16(pB0 + koff, ldsB0 + bo);
  };
  auto COMPUTE_K32 = [&](const char* ba, const char* bb, int kk) {
    // lane reads 8 fp8 at elem-offset kk*32 + lhi*8 of its row, swizzled granule
    const int pg = (((kk*2 + (lhi >> 1)) ^ (llo & 7)) << 4) + (lhi & 1)*8;
    long af[4], bfr[2];
    #pragma unroll
    for (int mi = 0; mi < 4; ++mi)
      af[mi] = *(const long*)(ba + (wr*64 + mi*16 + llo)*128 + pg);
    #pragma unroll
    for (int ni = 0; ni < 2; ++ni)
      bfr[ni] = *(const long*)(bb + (wc*32 + ni*16 + llo)*128 + pg);
    __builtin_amdgcn_s_setprio(1);
    #pragma unroll
    for (int mi = 0; mi < 4; ++mi)
      #pragma unroll
      for (int ni = 0; ni < 2; ++ni)
        acc[mi][ni] = __builtin_amdgcn_mfma_f32_16x16x32_fp8_fp8(af[mi], bfr[ni], acc[mi][ni], 0, 0, 0);
    __builtin_amdgcn_s_setprio(0);
  };

  // prologue: tiles 0 and 1 into bufs 0,1 (6 loads outstanding per wave)
  STAGE(0u, 0);
  STAGE(BUFSZ, 128);
  unsigned bsel = 0;  // (it % 3) * BUFSZ
  #pragma unroll 1
  for (int it = 0; it < 4; ++it) {
    if (it < 3) {
      asm volatile("s_waitcnt vmcnt(3)" ::: "memory");   // tile-it's 3 loads done
    } else {
      asm volatile("s_waitcnt vmcnt(0)" ::: "memory");
    }
    __builtin_amdgcn_s_barrier();     // all waves: tile-it DMA done & tile-(it-1) reads done
    asm volatile("" ::: "memory");
    const char* ba = smem + bsel;
    const char* bb = ba + 32768;
    unsigned nsel = bsel + 2*BUFSZ; if (nsel >= 3*BUFSZ) nsel -= 3*BUFSZ;  // (it+2)%3
    COMPUTE_K32(ba, bb, 0);
    if (it < 2) STAGE(nsel, (it + 2) * 128);             // stage tile it+2 (depth-2)
    COMPUTE_K32(ba, bb, 1);
    COMPUTE_K32(ba, bb, 2);
    COMPUTE_K32(ba, bb, 3);
    asm volatile("" ::: "memory");
    bsel += BUFSZ; if (bsel >= 3*BUFSZ) bsel = 0;
  }
  __syncthreads();  // smem about to be reused as dt (128KB, 256 tasks)

  // ---- single epilogue: acc -> ed(bf16) -> dt; acc dies here for ALL waves ----
  // dot = 256*cos (inputs scaled x16) -> ed = exp2(dot*KEXP/256 - KEXP)
  // dt element (l,m) of task T: T*512 + ((l*32+m*2) ^ ((l&12)<<3) ^ ((T&31)<<4))
  {
    const int ts = llo;
    #pragma unroll
    for (int ni = 0; ni < 2; ++ni) {
      int sloc = wc*2 + ni;                 // 0..7
      #pragma unroll
      for (int mi = 0; mi < 4; ++mi) {
        int qq = wr*4 + mi;                 // 0..15
        int T0 = (qq*8 + sloc) * 2;
        int T1 = T0 + 1;
        int swz0 = (T0 & 31) << 4, swz1 = (T1 & 31) << 4;
        u16x4 pk;
        #pragma unroll
        for (int j = 0; j < 4; ++j) {
          int tq = lhi*4 + j;
          float ed = EXP2F(fmaf(acc[mi][ni][j], KEXPS, -KEXP));
          u16 e16 = f2bf(ed);
          pk[j] = e16;
          *(u16*)(smem + T0*512 + ((tq*32 + ts*2) ^ ((tq&12)<<3) ^ swz0)) = e16;
        }
        *(u16x4*)(smem + T1*512 + ((ts*32 + lhi*8) ^ ((ts&12)<<3) ^ swz1)) = pk;
      }
    }
  }
  __syncthreads();

  // ---- exp-domain DP: 256 tasks, 16 waves x 16 active lanes ----
  if (lane < 16) {
    const int task = wave*16 + lane;        // 0..255
    const char* tb = smem + task * 512;
    const int swz = (task & 31) << 4;
    float F[18];
    {
      u16x8 g0 = *(const u16x8*)(tb + (0 ^ swz));
      u16x8 g1 = *(const u16x8*)(tb + (16 ^ swz));
      float c = 1.0f;
      F[0] = 1.0f;
      #pragma unroll
      for (int m = 1; m <= 8; ++m)  { c *= bf2f(g0[m-1]); F[m] = c; }
      #pragma unroll
      for (int m = 9; m <= 16; ++m) { c *= bf2f(g1[m-9]); F[m] = c; }
      F[17] = c;
    }
    u16x8 h0 = *(const u16x8*)(tb + ((32 ^ ((1&12)<<3)) ^ swz));
    u16x8 h1 = *(const u16x8*)(tb + (((32+16) ^ ((1&12)<<3)) ^ swz));
    float rowc = 1.0f;
    #pragma unroll 1
    for (int l = 1; l < 16; ++l) {
      u16x8 n0v, n1v;
      if (l < 15) {
        int lb = (l+1)*32, lx = ((l+1)&12)<<3;
        n0v = *(const u16x8*)(tb + ((lb ^ lx) ^ swz));
        n1v = *(const u16x8*)(tb + (((lb+16) ^ lx) ^ swz));
      }
      rowc *= K2;
      float e[16];
      #pragma unroll
      for (int m = 0; m < 8; ++m)  e[m]   = bf2f(h0[m]);
      #pragma unroll
      for (int m = 0; m < 8; ++m)  e[m+8] = bf2f(h1[m]);
      float c[18];
      c[1] = e[0]*K2*(F[0] + F[1]);            // edge m=1: 3 preds
      #pragma unroll
      for (int m = 2; m <= 16; ++m) c[m] = e[m-1]*K2*F[m-1];
      c[17] = K2*(F[16] + F[17]);              // edge m=17: 3 preds, ed=1
      F[0] = rowc;
      #pragma unroll
      for (int m = 1; m <= 16; ++m) F[m] = fmaf(e[m-1], F[m-1], c[m]);
      F[17] = F[16] + c[17];
      h0 = n0v; h1 = n1v;
    }
    float res = 15.0f - CLOG * LOG2F(F[17]);
    float other = __shfl_xor(res, 1);
    if (!(task & 1)) {
      int pair = task >> 1;                // 0..127
      int qq = pair >> 3, sl = pair & 7;
      out[(size_t)(by*16 + qq) * SN + bx*8 + sl] = res + other;
    }
  }
}

// ---------------- launch ----------------
extern "C" void kernel_launch(void* const* d_in, const int* in_sizes, int n_in,
                              void* d_out, int out_size, void* d_ws, size_t ws_size,
                              hipStream_t stream)
{
  const float* sup = (const float*)d_in[0];  // [128,16,512]
  const float* tgt = (const float*)d_in[1];  // [512,16,512]
  float* out = (float*)d_out;                // [512,128]
  char* ws = (char*)d_ws;

  char* A8 = ws;                             // 8192*512 = 4,194,304
  char* B8 = ws + 4194304;                   // 2048*512 = 1,048,576

  prep_kernel<<<dim3((QT + STF) / 4), dim3(256), 0, stream>>>(sup, tgt, A8, B8);
  fused_kernel<<<dim3(512), dim3(1024), 0, stream>>>(A8, B8, out);
}

// Round 20
// 37.749 us; speedup vs baseline: 1.1659x; 1.1659x over previous
//
#include <hip/hip_runtime.h>

typedef unsigned short u16;
typedef unsigned int u32;
typedef __attribute__((ext_vector_type(2))) unsigned int u32x2;
typedef __attribute__((ext_vector_type(4))) unsigned short u16x4;
typedef __attribute__((ext_vector_type(8))) unsigned short u16x8;
typedef __attribute__((ext_vector_type(4))) float f32x4;

#define QN 512
#define SN 128
#define DN 512
#define QT 8192   /* query frames */
#define STF 2048  /* support frames */

#if __has_builtin(__builtin_amdgcn_exp2f)
#define EXP2F __builtin_amdgcn_exp2f
#else
#define EXP2F exp2f
#endif
#if __has_builtin(__builtin_amdgcn_logf)
#define LOG2F __builtin_amdgcn_logf
#else
#define LOG2F log2f
#endif

#define KEXP 2.8853900817779268f     /* 1/(lbda*ln2), lbda=0.5 */
#define KEXPS (KEXP/256.0f)          /* compensates the x16 input scaling (16*16) */
#define CLOG 0.34657359027997264f    /* lbda*ln2 */
#define K2   7.38905609893065f       /* exp(1/lbda) = e^2 */
#define BUFSZ 49152u                 /* A 32KB + B 16KB per K=128 fp8 tile */

__device__ __forceinline__ u16 f2bf(float f){
  union { float f; unsigned int u; } v; v.f = f;
  unsigned int u = v.u;
  unsigned int r = (u + 0x7fffu + ((u >> 16) & 1u)) >> 16;
  return (u16)r;
}
__device__ __forceinline__ float bf2f(u16 v){
  union { unsigned int u; float f; } x; x.u = ((unsigned int)v) << 16; return x.f;
}

// f32 -> OCP e4m3fn, RNE; flush |x| < 2^-6 to +-0 (values here are ~N(0,0.7), max ~4)
__device__ __forceinline__ u32 f2e4m3(float x){
  union { float f; u32 u; } v; v.f = x;
  u32 s = (v.u >> 24) & 0x80u;
  float a = fabsf(x);
  if (a < 0.015625f) return s;
  u32 au = v.u & 0x7FFFFFFFu;
  u32 r = au + 0x7FFFFu + ((au >> 20) & 1u);   // RNE at mantissa bit 20
  u32 e = (r >> 23) - 127u + 7u;
  u32 m = (r >> 20) & 7u;
  return s | (e << 3) | m;
}

__device__ __forceinline__ void gld16(const void* g, unsigned lds_addr){
  __builtin_amdgcn_global_load_lds(
      (const __attribute__((address_space(1))) unsigned int*)(unsigned long long)g,
      (__attribute__((address_space(3))) unsigned int*)lds_addr,
      16, 0, 0);
}

// ---------------- prep: f32 -> fp8 e4m3 of 16*row/||row|| ----------------
__global__ __launch_bounds__(256) void prep_kernel(
    const float* __restrict__ sup, const float* __restrict__ tgt,
    char* __restrict__ A8, char* __restrict__ B8)
{
  int w = (int)((blockIdx.x * blockDim.x + threadIdx.x) >> 6);
  int lane = threadIdx.x & 63;
  if (w >= QT + STF) return;
  bool isQ = (w < QT);
  int row = isQ ? w : (w - QT);
  const float* src = (isQ ? tgt : sup) + (size_t)row * DN + lane * 8;
  f32x4 x0 = *(const f32x4*)src;
  f32x4 x1 = *(const f32x4*)(src + 4);
  float ss = 0.f;
  #pragma unroll
  for (int i = 0; i < 4; ++i) { ss += x0[i]*x0[i]; ss += x1[i]*x1[i]; }
  #pragma unroll
  for (int off = 32; off; off >>= 1) ss += __shfl_xor(ss, off);
  float inv = __builtin_amdgcn_rsqf(ss) * 16.0f;   // x16: dodge e4m3 subnormals
  u32 lo = 0, hi = 0;
  #pragma unroll
  for (int i = 0; i < 4; ++i) { lo |= f2e4m3(x0[i]*inv) << (8*i); hi |= f2e4m3(x1[i]*inv) << (8*i); }
  u32x2 o; o[0] = lo; o[1] = hi;
  char* dst = (isQ ? A8 : B8) + (size_t)row * DN + lane * 8;
  *(u32x2*)dst = o;
}

// ---------------- fused: 256x128 fp8 GEMM, BK=128, 4 iters, triple-buffer ----------
// == R15, the measured session optimum (36.9 us total; re-confirmed 37.45 in R18).
// 16q x 8s = 128 pairs x 2 dirs = 256 tasks x 512B = 128KB dt, overlaid on the
// 3 x 48KB staging buffers (147456 B). 8 waves; wave tile 64x64. Per K-tile/wave:
// 6 gld16 burst-issued (spread regressed, R16), 32 ds_read_b64 (2-way via
// 16B-granule XOR), 64 MFMA fp8 16x16x32, setprio around the MFMA cluster
// (benched-in at 36.9). vmcnt(6) depth-2 (R13 ledger), ONE barrier per tile.
// Occupancy variants (2/4 waves/SIMD, 1-generation, smaller acc) all regressed:
// R6/R8/R9/R10/R14/R17/R19. Wins came only from fewer bytes + fewer handshakes.
__global__ __launch_bounds__(512, 2) void fused_kernel(
    const char* __restrict__ A8, const char* __restrict__ B8,
    float* __restrict__ out)
{
  __shared__ __align__(128) char smem[147456];
  const int t = threadIdx.x;
  // XCD swizzle: 512 blocks, 64 consecutive work-ids per XCD
  const int bid = blockIdx.x;
  const int wsw = (bid & 7) * 64 + (bid >> 3);
  const int bx = wsw & 15, by = wsw >> 4;
  const int m0 = by * 256;   // query-frame base
  const int n0 = bx * 128;   // support-frame base
  const int wave = t >> 6, lane = t & 63;
  const int wr = wave >> 1, wc = wave & 1;
  const int lhi = lane >> 4, llo = lane & 15;

  const unsigned sbase = (unsigned)(unsigned long long)(void*)smem;

  // staging: row = 128B fp8 (K=128). gld16 covers 8 rows x 8 granules of 16B;
  // lane>>3 = row-sub, lane&7 = phys granule holding logical (lane&7)^rowsub.
  const int rsub = lane >> 3;
  const int lp = (lane & 7) ^ rsub;
  const char* pA[4]; unsigned ldsA[4];
  #pragma unroll
  for (int i = 0; i < 4; ++i) {
    int row = wave*32 + i*8 + rsub;                       // A: 256 rows, 32/wave
    pA[i] = A8 + (size_t)(m0 + row) * DN + lp*16;
    ldsA[i] = __builtin_amdgcn_readfirstlane(sbase + (unsigned)(wave*4096 + i*1024));
  }
  const char* pB[2]; unsigned ldsB[2];
  #pragma unroll
  for (int i = 0; i < 2; ++i) {
    int row = wave*16 + i*8 + rsub;                       // B: 128 rows, 16/wave
    pB[i] = B8 + (size_t)(n0 + row) * DN + lp*16;
    ldsB[i] = __builtin_amdgcn_readfirstlane(sbase + 32768u + (unsigned)(wave*2048 + i*1024));
  }

  f32x4 acc[4][4] = {};

  auto STAGE = [&](unsigned bo, int koff) {
    #pragma unroll
    for (int i = 0; i < 4; ++i) gld16(pA[i] + koff, ldsA[i] + bo);
    #pragma unroll
    for (int i = 0; i < 2; ++i) gld16(pB[i] + koff, ldsB[i] + bo);
  };
  auto COMPUTE_K32 = [&](const char* ba, const char* bb, int kk) {
    // lane reads 8 fp8 at elem-offset kk*32 + lhi*8 of its row, swizzled granule
    const int pg = (((kk*2 + (lhi >> 1)) ^ (llo & 7)) << 4) + (lhi & 1)*8;
    long af[4], bfr[4];
    #pragma unroll
    for (int mi = 0; mi < 4; ++mi)
      af[mi] = *(const long*)(ba + (wr*64 + mi*16 + llo)*128 + pg);
    #pragma unroll
    for (int ni = 0; ni < 4; ++ni)
      bfr[ni] = *(const long*)(bb + (wc*64 + ni*16 + llo)*128 + pg);
    __builtin_amdgcn_s_setprio(1);
    #pragma unroll
    for (int mi = 0; mi < 4; ++mi)
      #pragma unroll
      for (int ni = 0; ni < 4; ++ni)
        acc[mi][ni] = __builtin_amdgcn_mfma_f32_16x16x32_fp8_fp8(af[mi], bfr[ni], acc[mi][ni], 0, 0, 0);
    __builtin_amdgcn_s_setprio(0);
  };

  // prologue: tiles 0 and 1 into bufs 0,1 (12 loads outstanding)
  STAGE(0u, 0);
  STAGE(BUFSZ, 128);
  unsigned bsel = 0;  // (it % 3) * BUFSZ
  #pragma unroll 1
  for (int it = 0; it < 4; ++it) {
    if (it < 3) {
      asm volatile("s_waitcnt vmcnt(6)" ::: "memory");   // tile-it's 6 loads done
    } else {
      asm volatile("s_waitcnt vmcnt(0)" ::: "memory");
    }
    __builtin_amdgcn_s_barrier();     // all waves: tile-it DMA done & tile-(it-1) reads done
    asm volatile("" ::: "memory");
    const char* ba = smem + bsel;
    const char* bb = ba + 32768;
    unsigned nsel = bsel + 2*BUFSZ; if (nsel >= 3*BUFSZ) nsel -= 3*BUFSZ;  // (it+2)%3
    COMPUTE_K32(ba, bb, 0);
    if (it < 2) STAGE(nsel, (it + 2) * 128);             // stage tile it+2 (depth-2)
    COMPUTE_K32(ba, bb, 1);
    COMPUTE_K32(ba, bb, 2);
    COMPUTE_K32(ba, bb, 3);
    asm volatile("" ::: "memory");
    bsel += BUFSZ; if (bsel >= 3*BUFSZ) bsel = 0;
  }
  __syncthreads();  // smem about to be reused as dt (128KB, 256 tasks)

  // ---- single epilogue: acc -> ed(bf16) -> dt; acc dies here ----
  // dot = 256*cos (inputs scaled x16) -> ed = exp2(dot*KEXP/256 - KEXP)
  // dt element (l,m) of task T: T*512 + ((l*32+m*2) ^ ((l&12)<<3) ^ ((T&31)<<4))
  {
    const int ts = llo;
    #pragma unroll
    for (int ni = 0; ni < 4; ++ni) {
      int sloc = wc*4 + ni;                 // 0..7
      #pragma unroll
      for (int mi = 0; mi < 4; ++mi) {
        int qq = wr*4 + mi;                 // 0..15
        int T0 = (qq*8 + sloc) * 2;
        int T1 = T0 + 1;
        int swz0 = (T0 & 31) << 4, swz1 = (T1 & 31) << 4;
        u16x4 pk;
        #pragma unroll
        for (int j = 0; j < 4; ++j) {
          int tq = lhi*4 + j;
          float ed = EXP2F(fmaf(acc[mi][ni][j], KEXPS, -KEXP));
          u16 e16 = f2bf(ed);
          pk[j] = e16;
          *(u16*)(smem + T0*512 + ((tq*32 + ts*2) ^ ((tq&12)<<3) ^ swz0)) = e16;
        }
        *(u16x4*)(smem + T1*512 + ((ts*32 + lhi*8) ^ ((ts&12)<<3) ^ swz1)) = pk;
      }
    }
  }
  __syncthreads();

  // ---- exp-domain DP: 256 tasks, 8 waves x 32 active lanes ----
  if (lane < 32) {
    const int task = wave*32 + lane;        // 0..255
    const char* tb = smem + task * 512;
    const int swz = (task & 31) << 4;
    float F[18];
    {
      u16x8 g0 = *(const u16x8*)(tb + (0 ^ swz));
      u16x8 g1 = *(const u16x8*)(tb + (16 ^ swz));
      float c = 1.0f;
      F[0] = 1.0f;
      #pragma unroll
      for (int m = 1; m <= 8; ++m)  { c *= bf2f(g0[m-1]); F[m] = c; }
      #pragma unroll
      for (int m = 9; m <= 16; ++m) { c *= bf2f(g1[m-9]); F[m] = c; }
      F[17] = c;
    }
    u16x8 h0 = *(const u16x8*)(tb + ((32 ^ ((1&12)<<3)) ^ swz));
    u16x8 h1 = *(const u16x8*)(tb + (((32+16) ^ ((1&12)<<3)) ^ swz));
    float rowc = 1.0f;
    #pragma unroll 1
    for (int l = 1; l < 16; ++l) {
      u16x8 n0v, n1v;
      if (l < 15) {
        int lb = (l+1)*32, lx = ((l+1)&12)<<3;
        n0v = *(const u16x8*)(tb + ((lb ^ lx) ^ swz));
        n1v = *(const u16x8*)(tb + (((lb+16) ^ lx) ^ swz));
      }
      rowc *= K2;
      float e[16];
      #pragma unroll
      for (int m = 0; m < 8; ++m)  e[m]   = bf2f(h0[m]);
      #pragma unroll
      for (int m = 0; m < 8; ++m)  e[m+8] = bf2f(h1[m]);
      float c[18];
      c[1] = e[0]*K2*(F[0] + F[1]);            // edge m=1: 3 preds
      #pragma unroll
      for (int m = 2; m <= 16; ++m) c[m] = e[m-1]*K2*F[m-1];
      c[17] = K2*(F[16] + F[17]);              // edge m=17: 3 preds, ed=1
      F[0] = rowc;
      #pragma unroll
      for (int m = 1; m <= 16; ++m) F[m] = fmaf(e[m-1], F[m-1], c[m]);
      F[17] = F[16] + c[17];
      h0 = n0v; h1 = n1v;
    }
    float res = 15.0f - CLOG * LOG2F(F[17]);
    float other = __shfl_xor(res, 1);
    if (!(task & 1)) {
      int pair = task >> 1;                // 0..127
      int qq = pair >> 3, sl = pair & 7;
      out[(size_t)(by*16 + qq) * SN + bx*8 + sl] = res + other;
    }
  }
}

// ---------------- launch ----------------
extern "C" void kernel_launch(void* const* d_in, const int* in_sizes, int n_in,
                              void* d_out, int out_size, void* d_ws, size_t ws_size,
                              hipStream_t stream)
{
  const float* sup = (const float*)d_in[0];  // [128,16,512]
  const float* tgt = (const float*)d_in[1];  // [512,16,512]
  float* out = (float*)d_out;                // [512,128]
  char* ws = (char*)d_ws;

  char* A8 = ws;                             // 8192*512 = 4,194,304
  char* B8 = ws + 4194304;                   // 2048*512 = 1,048,576

  prep_kernel<<<dim3((QT + STF) / 4), dim3(256), 0, stream>>>(sup, tgt, A8, B8);
  fused_kernel<<<dim3(512), dim3(512), 0, stream>>>(A8, B8, out);
}

// Round 21
// 33.105 us; speedup vs baseline: 1.3295x; 1.1403x over previous
//
#include <hip/hip_runtime.h>

typedef unsigned short u16;
typedef unsigned int u32;
typedef __attribute__((ext_vector_type(2))) unsigned int u32x2;
typedef __attribute__((ext_vector_type(4))) unsigned int u32x4;
typedef __attribute__((ext_vector_type(8))) int i32x8;
typedef __attribute__((ext_vector_type(4))) unsigned short u16x4;
typedef __attribute__((ext_vector_type(8))) unsigned short u16x8;
typedef __attribute__((ext_vector_type(4))) float f32x4;

#define QN 512
#define SN 128
#define DN 512
#define QT 8192   /* query frames */
#define STF 2048  /* support frames */

#if __has_builtin(__builtin_amdgcn_exp2f)
#define EXP2F __builtin_amdgcn_exp2f
#else
#define EXP2F exp2f
#endif
#if __has_builtin(__builtin_amdgcn_logf)
#define LOG2F __builtin_amdgcn_logf
#else
#define LOG2F log2f
#endif

#define KEXP 2.8853900817779268f     /* 1/(lbda*ln2), lbda=0.5 */
#define KEXPS (KEXP/256.0f)          /* compensates the x16 input scaling (16*16) */
#define CLOG 0.34657359027997264f    /* lbda*ln2 */
#define K2   7.38905609893065f       /* exp(1/lbda) = e^2 */
#define BUFSZ 49152u                 /* A 32KB + B 16KB per K=128 fp8 tile */
#define SC1  0x7F7F7F7Fu             /* E8M0 unit scales (2^0 in every byte) */

__device__ __forceinline__ u16 f2bf(float f){
  union { float f; unsigned int u; } v; v.f = f;
  unsigned int u = v.u;
  unsigned int r = (u + 0x7fffu + ((u >> 16) & 1u)) >> 16;
  return (u16)r;
}
__device__ __forceinline__ float bf2f(u16 v){
  union { unsigned int u; float f; } x; x.u = ((unsigned int)v) << 16; return x.f;
}

// f32 -> OCP e4m3fn, RNE; flush |x| < 2^-6 to +-0 (values here are ~N(0,0.7), max ~4)
__device__ __forceinline__ u32 f2e4m3(float x){
  union { float f; u32 u; } v; v.f = x;
  u32 s = (v.u >> 24) & 0x80u;
  float a = fabsf(x);
  if (a < 0.015625f) return s;
  u32 au = v.u & 0x7FFFFFFFu;
  u32 r = au + 0x7FFFFu + ((au >> 20) & 1u);   // RNE at mantissa bit 20
  u32 e = (r >> 23) - 127u + 7u;
  u32 m = (r >> 20) & 7u;
  return s | (e << 3) | m;
}

__device__ __forceinline__ void gld16(const void* g, unsigned lds_addr){
  __builtin_amdgcn_global_load_lds(
      (const __attribute__((address_space(1))) unsigned int*)(unsigned long long)g,
      (__attribute__((address_space(3))) unsigned int*)lds_addr,
      16, 0, 0);
}

// ---------------- prep: f32 -> fp8 e4m3 of 16*row/||row|| ----------------
__global__ __launch_bounds__(256) void prep_kernel(
    const float* __restrict__ sup, const float* __restrict__ tgt,
    char* __restrict__ A8, char* __restrict__ B8)
{
  int w = (int)((blockIdx.x * blockDim.x + threadIdx.x) >> 6);
  int lane = threadIdx.x & 63;
  if (w >= QT + STF) return;
  bool isQ = (w < QT);
  int row = isQ ? w : (w - QT);
  const float* src = (isQ ? tgt : sup) + (size_t)row * DN + lane * 8;
  f32x4 x0 = *(const f32x4*)src;
  f32x4 x1 = *(const f32x4*)(src + 4);
  float ss = 0.f;
  #pragma unroll
  for (int i = 0; i < 4; ++i) { ss += x0[i]*x0[i]; ss += x1[i]*x1[i]; }
  #pragma unroll
  for (int off = 32; off; off >>= 1) ss += __shfl_xor(ss, off);
  float inv = __builtin_amdgcn_rsqf(ss) * 16.0f;   // x16: dodge e4m3 subnormals
  u32 lo = 0, hi = 0;
  #pragma unroll
  for (int i = 0; i < 4; ++i) { lo |= f2e4m3(x0[i]*inv) << (8*i); hi |= f2e4m3(x1[i]*inv) << (8*i); }
  u32x2 o; o[0] = lo; o[1] = hi;
  char* dst = (isQ ? A8 : B8) + (size_t)row * DN + lane * 8;
  *(u32x2*)dst = o;
}

// ---------------- fused: 256x128 MX-fp8 GEMM (K=128/instr), triple-buffer ----------
// R15's structure with the scaled MFMA: mfma_scale_f32_16x16x128_f8f6f4 at unit
// scales = numerically identical, 2x rate, 4x fewer MFMA instrs (16/tile/wave),
// 2x fewer LDS-read instrs (16 b128). Ladder-verified lever (m145->m148: +64%).
// 16q x 8s = 128 pairs x 2 dirs = 256 tasks x 512B = 128KB dt, overlaid on the
// 3 x 48KB staging buffers (147456 B). 8 waves; wave tile 64x64.
// vmcnt(6) depth-2 (R13 ledger), ONE barrier per tile -> 4 barriers total.
__global__ __launch_bounds__(512, 2) void fused_kernel(
    const char* __restrict__ A8, const char* __restrict__ B8,
    float* __restrict__ out)
{
  __shared__ __align__(128) char smem[147456];
  const int t = threadIdx.x;
  // XCD swizzle: 512 blocks, 64 consecutive work-ids per XCD
  const int bid = blockIdx.x;
  const int wsw = (bid & 7) * 64 + (bid >> 3);
  const int bx = wsw & 15, by = wsw >> 4;
  const int m0 = by * 256;   // query-frame base
  const int n0 = bx * 128;   // support-frame base
  const int wave = t >> 6, lane = t & 63;
  const int wr = wave >> 1, wc = wave & 1;
  const int lhi = lane >> 4, llo = lane & 15;

  const unsigned sbase = (unsigned)(unsigned long long)(void*)smem;

  // staging: row = 128B fp8 (K=128). gld16 covers 8 rows x 8 granules of 16B;
  // lane>>3 = row-sub, lane&7 = phys granule holding logical (lane&7)^rowsub.
  const int rsub = lane >> 3;
  const int lp = (lane & 7) ^ rsub;
  const char* pA[4]; unsigned ldsA[4];
  #pragma unroll
  for (int i = 0; i < 4; ++i) {
    int row = wave*32 + i*8 + rsub;                       // A: 256 rows, 32/wave
    pA[i] = A8 + (size_t)(m0 + row) * DN + lp*16;
    ldsA[i] = __builtin_amdgcn_readfirstlane(sbase + (unsigned)(wave*4096 + i*1024));
  }
  const char* pB[2]; unsigned ldsB[2];
  #pragma unroll
  for (int i = 0; i < 2; ++i) {
    int row = wave*16 + i*8 + rsub;                       // B: 128 rows, 16/wave
    pB[i] = B8 + (size_t)(n0 + row) * DN + lp*16;
    ldsB[i] = __builtin_amdgcn_readfirstlane(sbase + 32768u + (unsigned)(wave*2048 + i*1024));
  }

  f32x4 acc[4][4] = {};

  auto STAGE = [&](unsigned bo, int koff) {
    #pragma unroll
    for (int i = 0; i < 4; ++i) gld16(pA[i] + koff, ldsA[i] + bo);
    #pragma unroll
    for (int i = 0; i < 2; ++i) gld16(pB[i] + koff, ldsB[i] + bo);
  };

  // fragment: lane holds 32 fp8 of its row, k-bytes [lhi*32, +32) = logical
  // granules lhi*2, lhi*2+1; phys = logical ^ (row&7), row&7 == llo&7.
  const int x7 = llo & 7;
  auto LOADFRAG = [&](const char* rowp) -> i32x8 {
    union { u32x4 h[2]; i32x8 v; } f;
    f.h[0] = *(const u32x4*)(rowp + (((lhi*2 + 0) ^ x7) << 4));
    f.h[1] = *(const u32x4*)(rowp + (((lhi*2 + 1) ^ x7) << 4));
    return f.v;
  };

  // prologue: tiles 0 and 1 into bufs 0,1 (12 loads outstanding)
  STAGE(0u, 0);
  STAGE(BUFSZ, 128);
  unsigned bsel = 0;  // (it % 3) * BUFSZ
  #pragma unroll 1
  for (int it = 0; it < 4; ++it) {
    if (it < 3) {
      asm volatile("s_waitcnt vmcnt(6)" ::: "memory");   // tile-it's 6 loads done
    } else {
      asm volatile("s_waitcnt vmcnt(0)" ::: "memory");
    }
    __builtin_amdgcn_s_barrier();     // all waves: tile-it DMA done & tile-(it-1) reads done
    asm volatile("" ::: "memory");
    const char* ba = smem + bsel;
    const char* bb = ba + 32768;
    unsigned nsel = bsel + 2*BUFSZ; if (nsel >= 3*BUFSZ) nsel -= 3*BUFSZ;  // (it+2)%3
    i32x8 bfr[4];
    #pragma unroll
    for (int ni = 0; ni < 4; ++ni)
      bfr[ni] = LOADFRAG(bb + (wc*64 + ni*16 + llo)*128);
    i32x8 af[4];
    #pragma unroll
    for (int mi = 0; mi < 4; ++mi)
      af[mi] = LOADFRAG(ba + (wr*64 + mi*16 + llo)*128);
    if (it < 2) STAGE(nsel, (it + 2) * 128);             // stage tile it+2 (depth-2)
    __builtin_amdgcn_s_setprio(1);
    #pragma unroll
    for (int mi = 0; mi < 4; ++mi)
      #pragma unroll
      for (int ni = 0; ni < 4; ++ni)
        acc[mi][ni] = __builtin_amdgcn_mfma_scale_f32_16x16x128_f8f6f4(
            af[mi], bfr[ni], acc[mi][ni], 0, 0, 0, SC1, 0, SC1);
    __builtin_amdgcn_s_setprio(0);
    asm volatile("" ::: "memory");
    bsel += BUFSZ; if (bsel >= 3*BUFSZ) bsel = 0;
  }
  __syncthreads();  // smem about to be reused as dt (128KB, 256 tasks)

  // ---- single epilogue: acc -> ed(bf16) -> dt; acc dies here ----
  // dot = 256*cos (inputs scaled x16, unit MX scales) -> ed = exp2(dot*KEXP/256 - KEXP)
  // dt element (l,m) of task T: T*512 + ((l*32+m*2) ^ ((l&12)<<3) ^ ((T&31)<<4))
  {
    const int ts = llo;
    #pragma unroll
    for (int ni = 0; ni < 4; ++ni) {
      int sloc = wc*4 + ni;                 // 0..7
      #pragma unroll
      for (int mi = 0; mi < 4; ++mi) {
        int qq = wr*4 + mi;                 // 0..15
        int T0 = (qq*8 + sloc) * 2;
        int T1 = T0 + 1;
        int swz0 = (T0 & 31) << 4, swz1 = (T1 & 31) << 4;
        u16x4 pk;
        #pragma unroll
        for (int j = 0; j < 4; ++j) {
          int tq = lhi*4 + j;
          float ed = EXP2F(fmaf(acc[mi][ni][j], KEXPS, -KEXP));
          u16 e16 = f2bf(ed);
          pk[j] = e16;
          *(u16*)(smem + T0*512 + ((tq*32 + ts*2) ^ ((tq&12)<<3) ^ swz0)) = e16;
        }
        *(u16x4*)(smem + T1*512 + ((ts*32 + lhi*8) ^ ((ts&12)<<3) ^ swz1)) = pk;
      }
    }
  }
  __syncthreads();

  // ---- exp-domain DP: 256 tasks, 8 waves x 32 active lanes ----
  if (lane < 32) {
    const int task = wave*32 + lane;        // 0..255
    const char* tb = smem + task * 512;
    const int swz = (task & 31) << 4;
    float F[18];
    {
      u16x8 g0 = *(const u16x8*)(tb + (0 ^ swz));
      u16x8 g1 = *(const u16x8*)(tb + (16 ^ swz));
      float c = 1.0f;
      F[0] = 1.0f;
      #pragma unroll
      for (int m = 1; m <= 8; ++m)  { c *= bf2f(g0[m-1]); F[m] = c; }
      #pragma unroll
      for (int m = 9; m <= 16; ++m) { c *= bf2f(g1[m-9]); F[m] = c; }
      F[17] = c;
    }
    u16x8 h0 = *(const u16x8*)(tb + ((32 ^ ((1&12)<<3)) ^ swz));
    u16x8 h1 = *(const u16x8*)(tb + (((32+16) ^ ((1&12)<<3)) ^ swz));
    float rowc = 1.0f;
    #pragma unroll 1
    for (int l = 1; l < 16; ++l) {
      u16x8 n0v, n1v;
      if (l < 15) {
        int lb = (l+1)*32, lx = ((l+1)&12)<<3;
        n0v = *(const u16x8*)(tb + ((lb ^ lx) ^ swz));
        n1v = *(const u16x8*)(tb + (((lb+16) ^ lx) ^ swz));
      }
      rowc *= K2;
      float e[16];
      #pragma unroll
      for (int m = 0; m < 8; ++m)  e[m]   = bf2f(h0[m]);
      #pragma unroll
      for (int m = 0; m < 8; ++m)  e[m+8] = bf2f(h1[m]);
      float c[18];
      c[1] = e[0]*K2*(F[0] + F[1]);            // edge m=1: 3 preds
      #pragma unroll
      for (int m = 2; m <= 16; ++m) c[m] = e[m-1]*K2*F[m-1];
      c[17] = K2*(F[16] + F[17]);              // edge m=17: 3 preds, ed=1
      F[0] = rowc;
      #pragma unroll
      for (int m = 1; m <= 16; ++m) F[m] = fmaf(e[m-1], F[m-1], c[m]);
      F[17] = F[16] + c[17];
      h0 = n0v; h1 = n1v;
    }
    float res = 15.0f - CLOG * LOG2F(F[17]);
    float other = __shfl_xor(res, 1);
    if (!(task & 1)) {
      int pair = task >> 1;                // 0..127
      int qq = pair >> 3, sl = pair & 7;
      out[(size_t)(by*16 + qq) * SN + bx*8 + sl] = res + other;
    }
  }
}

// ---------------- launch ----------------
extern "C" void kernel_launch(void* const* d_in, const int* in_sizes, int n_in,
                              void* d_out, int out_size, void* d_ws, size_t ws_size,
                              hipStream_t stream)
{
  const float* sup = (const float*)d_in[0];  // [128,16,512]
  const float* tgt = (const float*)d_in[1];  // [512,16,512]
  float* out = (float*)d_out;                // [512,128]
  char* ws = (char*)d_ws;

  char* A8 = ws;                             // 8192*512 = 4,194,304
  char* B8 = ws + 4194304;                   // 2048*512 = 1,048,576

  prep_kernel<<<dim3((QT + STF) / 4), dim3(256), 0, stream>>>(sup, tgt, A8, B8);
  fused_kernel<<<dim3(512), dim3(512), 0, stream>>>(A8, B8, out);
}

// Round 22
// 33.102 us; speedup vs baseline: 1.3296x; 1.0001x over previous
//
#include <hip/hip_runtime.h>

typedef unsigned short u16;
typedef unsigned int u32;
typedef __attribute__((ext_vector_type(2))) unsigned int u32x2;
typedef __attribute__((ext_vector_type(4))) unsigned int u32x4;
typedef __attribute__((ext_vector_type(8))) int i32x8;
typedef __attribute__((ext_vector_type(4))) unsigned short u16x4;
typedef __attribute__((ext_vector_type(8))) unsigned short u16x8;
typedef __attribute__((ext_vector_type(4))) float f32x4;

#define QN 512
#define SN 128
#define DN 512
#define QT 8192   /* query frames */
#define STF 2048  /* support frames */

#if __has_builtin(__builtin_amdgcn_exp2f)
#define EXP2F __builtin_amdgcn_exp2f
#else
#define EXP2F exp2f
#endif
#if __has_builtin(__builtin_amdgcn_logf)
#define LOG2F __builtin_amdgcn_logf
#else
#define LOG2F log2f
#endif

#define KEXP 2.8853900817779268f     /* 1/(lbda*ln2), lbda=0.5 */
#define KEXPS (KEXP/256.0f)          /* compensates the x16 input scaling (16*16) */
#define CLOG 0.34657359027997264f    /* lbda*ln2 */
#define K2   7.38905609893065f       /* exp(1/lbda) = e^2 */
#define BUFSZ 49152u                 /* A 32KB + B 16KB per K=128 fp8 tile */
#define SC1  0x7F7F7F7Fu             /* E8M0 unit scales (2^0 in every byte) */

__device__ __forceinline__ u16 f2bf(float f){
  union { float f; unsigned int u; } v; v.f = f;
  unsigned int u = v.u;
  unsigned int r = (u + 0x7fffu + ((u >> 16) & 1u)) >> 16;
  return (u16)r;
}
__device__ __forceinline__ float bf2f(u16 v){
  union { unsigned int u; float f; } x; x.u = ((unsigned int)v) << 16; return x.f;
}

// f32 -> OCP e4m3fn, RNE; flush |x| < 2^-6 to +-0 (values here are ~N(0,0.7), max ~4)
__device__ __forceinline__ u32 f2e4m3(float x){
  union { float f; u32 u; } v; v.f = x;
  u32 s = (v.u >> 24) & 0x80u;
  float a = fabsf(x);
  if (a < 0.015625f) return s;
  u32 au = v.u & 0x7FFFFFFFu;
  u32 r = au + 0x7FFFFu + ((au >> 20) & 1u);   // RNE at mantissa bit 20
  u32 e = (r >> 23) - 127u + 7u;
  u32 m = (r >> 20) & 7u;
  return s | (e << 3) | m;
}

__device__ __forceinline__ void gld16(const void* g, unsigned lds_addr){
  __builtin_amdgcn_global_load_lds(
      (const __attribute__((address_space(1))) unsigned int*)(unsigned long long)g,
      (__attribute__((address_space(3))) unsigned int*)lds_addr,
      16, 0, 0);
}

// ---------------- prep: f32 -> fp8 e4m3 of 16*row/||row|| ----------------
__global__ __launch_bounds__(256) void prep_kernel(
    const float* __restrict__ sup, const float* __restrict__ tgt,
    char* __restrict__ A8, char* __restrict__ B8)
{
  int w = (int)((blockIdx.x * blockDim.x + threadIdx.x) >> 6);
  int lane = threadIdx.x & 63;
  if (w >= QT + STF) return;
  bool isQ = (w < QT);
  int row = isQ ? w : (w - QT);
  const float* src = (isQ ? tgt : sup) + (size_t)row * DN + lane * 8;
  f32x4 x0 = *(const f32x4*)src;
  f32x4 x1 = *(const f32x4*)(src + 4);
  float ss = 0.f;
  #pragma unroll
  for (int i = 0; i < 4; ++i) { ss += x0[i]*x0[i]; ss += x1[i]*x1[i]; }
  #pragma unroll
  for (int off = 32; off; off >>= 1) ss += __shfl_xor(ss, off);
  float inv = __builtin_amdgcn_rsqf(ss) * 16.0f;   // x16: dodge e4m3 subnormals
  u32 lo = 0, hi = 0;
  #pragma unroll
  for (int i = 0; i < 4; ++i) { lo |= f2e4m3(x0[i]*inv) << (8*i); hi |= f2e4m3(x1[i]*inv) << (8*i); }
  u32x2 o; o[0] = lo; o[1] = hi;
  char* dst = (isQ ? A8 : B8) + (size_t)row * DN + lane * 8;
  *(u32x2*)dst = o;
}

// ---------------- fused: 256x128 MX-fp8 GEMM (K=128/instr), triple-buffer ----------
// SESSION FINAL (R21, 33.1 us; 3.03x over round-1 baseline). R15 structure with the
// scaled MFMA: mfma_scale_f32_16x16x128_f8f6f4 at unit scales = numerically identical
// to non-scaled fp8, 2x rate, 4x fewer MFMA instrs, 2x fewer LDS-read instrs
// (ladder m145->m148 lever). 16q x 8s = 128 pairs x 2 dirs = 256 tasks x 512B =
// 128KB dt, overlaid on 3 x 48KB staging buffers (147456 B LDS). 8 waves, tile 64x64.
// vmcnt(6) depth-2 (R13 ledger), ONE barrier per tile -> 4 barriers total.
// Falsified families (do not revisit): occupancy/one-generation (R6/8/9/10/14/17/19),
// deeper pipelining/barrier variants (R5/11/12), STAGE-spread/setprio-removal (R16).
__global__ __launch_bounds__(512, 2) void fused_kernel(
    const char* __restrict__ A8, const char* __restrict__ B8,
    float* __restrict__ out)
{
  __shared__ __align__(128) char smem[147456];
  const int t = threadIdx.x;
  // XCD swizzle: 512 blocks, 64 consecutive work-ids per XCD
  const int bid = blockIdx.x;
  const int wsw = (bid & 7) * 64 + (bid >> 3);
  const int bx = wsw & 15, by = wsw >> 4;
  const int m0 = by * 256;   // query-frame base
  const int n0 = bx * 128;   // support-frame base
  const int wave = t >> 6, lane = t & 63;
  const int wr = wave >> 1, wc = wave & 1;
  const int lhi = lane >> 4, llo = lane & 15;

  const unsigned sbase = (unsigned)(unsigned long long)(void*)smem;

  // staging: row = 128B fp8 (K=128). gld16 covers 8 rows x 8 granules of 16B;
  // lane>>3 = row-sub, lane&7 = phys granule holding logical (lane&7)^rowsub.
  const int rsub = lane >> 3;
  const int lp = (lane & 7) ^ rsub;
  const char* pA[4]; unsigned ldsA[4];
  #pragma unroll
  for (int i = 0; i < 4; ++i) {
    int row = wave*32 + i*8 + rsub;                       // A: 256 rows, 32/wave
    pA[i] = A8 + (size_t)(m0 + row) * DN + lp*16;
    ldsA[i] = __builtin_amdgcn_readfirstlane(sbase + (unsigned)(wave*4096 + i*1024));
  }
  const char* pB[2]; unsigned ldsB[2];
  #pragma unroll
  for (int i = 0; i < 2; ++i) {
    int row = wave*16 + i*8 + rsub;                       // B: 128 rows, 16/wave
    pB[i] = B8 + (size_t)(n0 + row) * DN + lp*16;
    ldsB[i] = __builtin_amdgcn_readfirstlane(sbase + 32768u + (unsigned)(wave*2048 + i*1024));
  }

  f32x4 acc[4][4] = {};

  auto STAGE = [&](unsigned bo, int koff) {
    #pragma unroll
    for (int i = 0; i < 4; ++i) gld16(pA[i] + koff, ldsA[i] + bo);
    #pragma unroll
    for (int i = 0; i < 2; ++i) gld16(pB[i] + koff, ldsB[i] + bo);
  };

  // fragment: lane holds 32 fp8 of its row, k-bytes [lhi*32, +32) = logical
  // granules lhi*2, lhi*2+1; phys = logical ^ (row&7), row&7 == llo&7.
  const int x7 = llo & 7;
  auto LOADFRAG = [&](const char* rowp) -> i32x8 {
    union { u32x4 h[2]; i32x8 v; } f;
    f.h[0] = *(const u32x4*)(rowp + (((lhi*2 + 0) ^ x7) << 4));
    f.h[1] = *(const u32x4*)(rowp + (((lhi*2 + 1) ^ x7) << 4));
    return f.v;
  };

  // prologue: tiles 0 and 1 into bufs 0,1 (12 loads outstanding)
  STAGE(0u, 0);
  STAGE(BUFSZ, 128);
  unsigned bsel = 0;  // (it % 3) * BUFSZ
  #pragma unroll 1
  for (int it = 0; it < 4; ++it) {
    if (it < 3) {
      asm volatile("s_waitcnt vmcnt(6)" ::: "memory");   // tile-it's 6 loads done
    } else {
      asm volatile("s_waitcnt vmcnt(0)" ::: "memory");
    }
    __builtin_amdgcn_s_barrier();     // all waves: tile-it DMA done & tile-(it-1) reads done
    asm volatile("" ::: "memory");
    const char* ba = smem + bsel;
    const char* bb = ba + 32768;
    unsigned nsel = bsel + 2*BUFSZ; if (nsel >= 3*BUFSZ) nsel -= 3*BUFSZ;  // (it+2)%3
    i32x8 bfr[4];
    #pragma unroll
    for (int ni = 0; ni < 4; ++ni)
      bfr[ni] = LOADFRAG(bb + (wc*64 + ni*16 + llo)*128);
    i32x8 af[4];
    #pragma unroll
    for (int mi = 0; mi < 4; ++mi)
      af[mi] = LOADFRAG(ba + (wr*64 + mi*16 + llo)*128);
    if (it < 2) STAGE(nsel, (it + 2) * 128);             // stage tile it+2 (depth-2)
    __builtin_amdgcn_s_setprio(1);
    #pragma unroll
    for (int mi = 0; mi < 4; ++mi)
      #pragma unroll
      for (int ni = 0; ni < 4; ++ni)
        acc[mi][ni] = __builtin_amdgcn_mfma_scale_f32_16x16x128_f8f6f4(
            af[mi], bfr[ni], acc[mi][ni], 0, 0, 0, SC1, 0, SC1);
    __builtin_amdgcn_s_setprio(0);
    asm volatile("" ::: "memory");
    bsel += BUFSZ; if (bsel >= 3*BUFSZ) bsel = 0;
  }
  __syncthreads();  // smem about to be reused as dt (128KB, 256 tasks)

  // ---- single epilogue: acc -> ed(bf16) -> dt; acc dies here ----
  // dot = 256*cos (inputs scaled x16, unit MX scales) -> ed = exp2(dot*KEXP/256 - KEXP)
  // dt element (l,m) of task T: T*512 + ((l*32+m*2) ^ ((l&12)<<3) ^ ((T&31)<<4))
  {
    const int ts = llo;
    #pragma unroll
    for (int ni = 0; ni < 4; ++ni) {
      int sloc = wc*4 + ni;                 // 0..7
      #pragma unroll
      for (int mi = 0; mi < 4; ++mi) {
        int qq = wr*4 + mi;                 // 0..15
        int T0 = (qq*8 + sloc) * 2;
        int T1 = T0 + 1;
        int swz0 = (T0 & 31) << 4, swz1 = (T1 & 31) << 4;
        u16x4 pk;
        #pragma unroll
        for (int j = 0; j < 4; ++j) {
          int tq = lhi*4 + j;
          float ed = EXP2F(fmaf(acc[mi][ni][j], KEXPS, -KEXP));
          u16 e16 = f2bf(ed);
          pk[j] = e16;
          *(u16*)(smem + T0*512 + ((tq*32 + ts*2) ^ ((tq&12)<<3) ^ swz0)) = e16;
        }
        *(u16x4*)(smem + T1*512 + ((ts*32 + lhi*8) ^ ((ts&12)<<3) ^ swz1)) = pk;
      }
    }
  }
  __syncthreads();

  // ---- exp-domain DP: 256 tasks, 8 waves x 32 active lanes ----
  if (lane < 32) {
    const int task = wave*32 + lane;        // 0..255
    const char* tb = smem + task * 512;
    const int swz = (task & 31) << 4;
    float F[18];
    {
      u16x8 g0 = *(const u16x8*)(tb + (0 ^ swz));
      u16x8 g1 = *(const u16x8*)(tb + (16 ^ swz));
      float c = 1.0f;
      F[0] = 1.0f;
      #pragma unroll
      for (int m = 1; m <= 8; ++m)  { c *= bf2f(g0[m-1]); F[m] = c; }
      #pragma unroll
      for (int m = 9; m <= 16; ++m) { c *= bf2f(g1[m-9]); F[m] = c; }
      F[17] = c;
    }
    u16x8 h0 = *(const u16x8*)(tb + ((32 ^ ((1&12)<<3)) ^ swz));
    u16x8 h1 = *(const u16x8*)(tb + (((32+16) ^ ((1&12)<<3)) ^ swz));
    float rowc = 1.0f;
    #pragma unroll 1
    for (int l = 1; l < 16; ++l) {
      u16x8 n0v, n1v;
      if (l < 15) {
        int lb = (l+1)*32, lx = ((l+1)&12)<<3;
        n0v = *(const u16x8*)(tb + ((lb ^ lx) ^ swz));
        n1v = *(const u16x8*)(tb + (((lb+16) ^ lx) ^ swz));
      }
      rowc *= K2;
      float e[16];
      #pragma unroll
      for (int m = 0; m < 8; ++m)  e[m]   = bf2f(h0[m]);
      #pragma unroll
      for (int m = 0; m < 8; ++m)  e[m+8] = bf2f(h1[m]);
      float c[18];
      c[1] = e[0]*K2*(F[0] + F[1]);            // edge m=1: 3 preds
      #pragma unroll
      for (int m = 2; m <= 16; ++m) c[m] = e[m-1]*K2*F[m-1];
      c[17] = K2*(F[16] + F[17]);              // edge m=17: 3 preds, ed=1
      F[0] = rowc;
      #pragma unroll
      for (int m = 1; m <= 16; ++m) F[m] = fmaf(e[m-1], F[m-1], c[m]);
      F[17] = F[16] + c[17];
      h0 = n0v; h1 = n1v;
    }
    float res = 15.0f - CLOG * LOG2F(F[17]);
    float other = __shfl_xor(res, 1);
    if (!(task & 1)) {
      int pair = task >> 1;                // 0..127
      int qq = pair >> 3, sl = pair & 7;
      out[(size_t)(by*16 + qq) * SN + bx*8 + sl] = res + other;
    }
  }
}

// ---------------- launch ----------------
extern "C" void kernel_launch(void* const* d_in, const int* in_sizes, int n_in,
                              void* d_out, int out_size, void* d_ws, size_t ws_size,
                              hipStream_t stream)
{
  const float* sup = (const float*)d_in[0];  // [128,16,512]
  const float* tgt = (const float*)d_in[1];  // [512,16,512]
  float* out = (float*)d_out;                // [512,128]
  char* ws = (char*)d_ws;

  char* A8 = ws;                             // 8192*512 = 4,194,304
  char* B8 = ws + 4194304;                   // 2048*512 = 1,048,576

  prep_kernel<<<dim3((QT + STF) / 4), dim3(256), 0, stream>>>(sup, tgt, A8, B8);
  fused_kernel<<<dim3(512), dim3(512), 0, stream>>>(A8, B8, out);
}